// Round 1
// baseline (300.194 us; speedup 1.0000x reference)
//
#include <hip/hip_runtime.h>
#include <math.h>

// ---------------------------------------------------------------------------
// Deep4Net fused pipeline, fp32.
//   conv1(time k10) + conv2(spat 22ch) fused into one combined conv (linear).
//   pool(elu(x)) == elu(pool(x))  (ELU monotonic) -> max3 then one expf.
// Workspace layout (floats):
//   [0      .. 5500)   Wc[o][c][k]  (o*220 + c*10 + k)
//   [5504   .. 5529)   bc[o]
//   [5536   .. +2112000) p1[b][o][t]  (256 x 25 x 330)
// ---------------------------------------------------------------------------

#define WS_WC 0
#define WS_BC 5504
#define WS_P1 5536

__device__ __forceinline__ float elu1(float v) {
    return v > 0.f ? v : __expf(v) - 1.f;
}

// ---- K0: combine conv1/conv2 weights -------------------------------------
__global__ __launch_bounds__(256) void k_prep(const float* __restrict__ wt,
                                              const float* __restrict__ bt,
                                              const float* __restrict__ wsp,
                                              const float* __restrict__ bsp,
                                              float* __restrict__ ws) {
    int idx = blockIdx.x * 256 + threadIdx.x;
    if (idx < 5500) {
        int o = idx / 220, r = idx - o * 220;
        int c = r / 10, k = r - c * 10;
        float s = 0.f;
        for (int i = 0; i < 25; ++i)
            s += wt[i * 10 + k] * wsp[(o * 25 + i) * 22 + c];
        ws[WS_WC + idx] = s;
    } else if (idx < 5525) {
        int o = idx - 5500;
        float s = bsp[o];
        for (int i = 0; i < 25; ++i) {
            float rs = 0.f;
            for (int c = 0; c < 22; ++c) rs += wsp[(o * 25 + i) * 22 + c];
            s += bt[i] * rs;
        }
        ws[WS_BC + o] = s;
    }
}

// ---- K1: combined conv + ELU + pool3 -> p1[b][25][330] --------------------
// grid (3, 256): blockIdx.y = sample, blockIdx.x = 110-tp chunk
__global__ __launch_bounds__(256) void k_conv12(const float* __restrict__ x,
                                                const float* __restrict__ ws,
                                                float* __restrict__ p1) {
    const float* Wc = ws + WS_WC;
    const float* bc = ws + WS_BC;
    int b = blockIdx.y;
    int chunk = blockIdx.x;
    __shared__ float xs[22][340];
    int tid = threadIdx.x;
    int t0 = chunk * 330;
    for (int i = tid; i < 22 * 339; i += 256) {
        int c = i / 339, tt = i - c * 339;
        xs[c][tt] = x[b * 22000 + c * 1000 + t0 + tt];
    }
    __syncthreads();
    // 275 items = 5 o-groups (5 o's each) x 55 tp-groups (2 pooled tps each)
    for (int item = tid; item < 275; item += 256) {
        int og = item / 55, tpg = item - og * 55;
        int o0 = og * 5;
        int tl = tpg * 6;  // 3 * (2*tpg)
        float acc[5][6];
#pragma unroll
        for (int oo = 0; oo < 5; ++oo) {
            float bv = bc[o0 + oo];
#pragma unroll
            for (int j = 0; j < 6; ++j) acc[oo][j] = bv;
        }
        for (int c = 0; c < 22; ++c) {
            float xv[15];
#pragma unroll
            for (int q = 0; q < 15; ++q) xv[q] = xs[c][tl + q];
#pragma unroll
            for (int oo = 0; oo < 5; ++oo) {
                const float* wr = Wc + (o0 + oo) * 220 + c * 10;
#pragma unroll
                for (int k = 0; k < 10; ++k) {
                    float w = wr[k];
#pragma unroll
                    for (int j = 0; j < 6; ++j)
                        acc[oo][j] = fmaf(xv[j + k], w, acc[oo][j]);
                }
            }
        }
        int tp0 = chunk * 110 + tpg * 2;
#pragma unroll
        for (int oo = 0; oo < 5; ++oo) {
            float m0 = fmaxf(fmaxf(acc[oo][0], acc[oo][1]), acc[oo][2]);
            float m1 = fmaxf(fmaxf(acc[oo][3], acc[oo][4]), acc[oo][5]);
            p1[(b * 25 + o0 + oo) * 330 + tp0] = elu1(m0);
            p1[(b * 25 + o0 + oo) * 330 + tp0 + 1] = elu1(m1);
        }
    }
}

// ---- K2: conv3 -> conv4 -> conv5 -> head, one block per sample ------------
// LDS overlay (floats):
//   p1s: [0, 8300)      25 rows x 332
//   p2s: [8300, 13700)  50 rows x 108 (107 valid)
//   p3s: [0, 3200)      100 rows x 32   (p1s dead by then)
//   p4s: [3300, 4700)   1400 feats      (p2s dead by then)
__global__ __launch_bounds__(256) void k_rest(
    const float* __restrict__ p1g,
    const float* __restrict__ w2, const float* __restrict__ b2,
    const float* __restrict__ w3, const float* __restrict__ b3,
    const float* __restrict__ w4, const float* __restrict__ b4,
    const float* __restrict__ hW, const float* __restrict__ hB,
    const int* __restrict__ sid, float* __restrict__ out) {
    __shared__ float buf[13700];
    float* p1s = buf;
    float* p2s = buf + 8300;
    float* p3s = buf;
    float* p4s = buf + 3300;
    int b = blockIdx.x;
    int tid = threadIdx.x;

    for (int i = tid; i < 8250; i += 256) {
        int o = i / 330, t = i - o * 330;
        p1s[o * 332 + t] = p1g[b * 8250 + i];
    }
    __syncthreads();

    // conv3 (w2): [25][330] -> [50][107], items = 25 og(x2 o) * 27 tpg(x4 tp)
    for (int item = tid; item < 675; item += 256) {
        int og = item / 27, tpg = item - og * 27;
        int o0 = og * 2;
        int tl = tpg * 12;
        float acc0[12], acc1[12];
        float bb0 = b2[o0], bb1 = b2[o0 + 1];
#pragma unroll
        for (int j = 0; j < 12; ++j) { acc0[j] = bb0; acc1[j] = bb1; }
        for (int i = 0; i < 25; ++i) {
            float xv[21];
#pragma unroll
            for (int q = 0; q < 21; ++q) xv[q] = p1s[i * 332 + tl + q];
            const float* wr0 = w2 + (o0 * 25 + i) * 10;
            const float* wr1 = wr0 + 250;
#pragma unroll
            for (int k = 0; k < 10; ++k) {
                float w0 = wr0[k], w1 = wr1[k];
#pragma unroll
                for (int j = 0; j < 12; ++j) {
                    acc0[j] = fmaf(xv[j + k], w0, acc0[j]);
                    acc1[j] = fmaf(xv[j + k], w1, acc1[j]);
                }
            }
        }
#pragma unroll
        for (int q = 0; q < 4; ++q) {
            int tp = tpg * 4 + q;
            if (tp < 107) {
                float m0 = fmaxf(fmaxf(acc0[3 * q], acc0[3 * q + 1]), acc0[3 * q + 2]);
                float m1 = fmaxf(fmaxf(acc1[3 * q], acc1[3 * q + 1]), acc1[3 * q + 2]);
                p2s[o0 * 108 + tp] = elu1(m0);
                p2s[(o0 + 1) * 108 + tp] = elu1(m1);
            }
        }
    }
    __syncthreads();

    // conv4 (w3): [50][107] -> [100][32], items = 50 og * 8 tpg
    for (int item = tid; item < 400; item += 256) {
        int og = item / 8, tpg = item - og * 8;
        int o0 = og * 2;
        int tl = tpg * 12;
        float acc0[12], acc1[12];
        float bb0 = b3[o0], bb1 = b3[o0 + 1];
#pragma unroll
        for (int j = 0; j < 12; ++j) { acc0[j] = bb0; acc1[j] = bb1; }
        for (int i = 0; i < 50; ++i) {
            float xv[21];
#pragma unroll
            for (int q = 0; q < 21; ++q) xv[q] = p2s[i * 108 + tl + q];
            const float* wr0 = w3 + (o0 * 50 + i) * 10;
            const float* wr1 = wr0 + 500;
#pragma unroll
            for (int k = 0; k < 10; ++k) {
                float w0 = wr0[k], w1 = wr1[k];
#pragma unroll
                for (int j = 0; j < 12; ++j) {
                    acc0[j] = fmaf(xv[j + k], w0, acc0[j]);
                    acc1[j] = fmaf(xv[j + k], w1, acc1[j]);
                }
            }
        }
#pragma unroll
        for (int q = 0; q < 4; ++q) {
            int tp = tpg * 4 + q;
            float m0 = fmaxf(fmaxf(acc0[3 * q], acc0[3 * q + 1]), acc0[3 * q + 2]);
            float m1 = fmaxf(fmaxf(acc1[3 * q], acc1[3 * q + 1]), acc1[3 * q + 2]);
            p3s[o0 * 32 + tp] = elu1(m0);
            p3s[(o0 + 1) * 32 + tp] = elu1(m1);
        }
    }
    __syncthreads();

    // conv5 (w4): [100][32] -> [200][7], items = 100 og(x2 o) * 4 i-chunks
    // lane quads hold the 4 i-chunks of one og -> shfl_xor reduce
    for (int item = tid; item < 400; item += 256) {
        int og = item >> 2, is = item & 3;
        int o0 = og * 2;
        int i0 = is * 25;
        float acc0[21], acc1[21];
#pragma unroll
        for (int j = 0; j < 21; ++j) { acc0[j] = 0.f; acc1[j] = 0.f; }
        for (int ii = 0; ii < 25; ++ii) {
            int i = i0 + ii;
            float xv[30];
#pragma unroll
            for (int q = 0; q < 30; ++q) xv[q] = p3s[i * 32 + q];
            const float* wr0 = w4 + (o0 * 100 + i) * 10;
            const float* wr1 = wr0 + 1000;
#pragma unroll
            for (int k = 0; k < 10; ++k) {
                float w0 = wr0[k], w1 = wr1[k];
#pragma unroll
                for (int j = 0; j < 21; ++j) {
                    acc0[j] = fmaf(xv[j + k], w0, acc0[j]);
                    acc1[j] = fmaf(xv[j + k], w1, acc1[j]);
                }
            }
        }
#pragma unroll
        for (int j = 0; j < 21; ++j) {
            acc0[j] += __shfl_xor(acc0[j], 1);
            acc0[j] += __shfl_xor(acc0[j], 2);
            acc1[j] += __shfl_xor(acc1[j], 1);
            acc1[j] += __shfl_xor(acc1[j], 2);
        }
        if (is == 0) {
            float bb0 = b4[o0], bb1 = b4[o0 + 1];
#pragma unroll
            for (int tp = 0; tp < 7; ++tp) {
                float m0 = fmaxf(fmaxf(acc0[3 * tp], acc0[3 * tp + 1]), acc0[3 * tp + 2]) + bb0;
                float m1 = fmaxf(fmaxf(acc1[3 * tp], acc1[3 * tp + 1]), acc1[3 * tp + 2]) + bb1;
                p4s[o0 * 7 + tp] = elu1(m0);
                p4s[(o0 + 1) * 7 + tp] = elu1(m1);
            }
        }
    }
    __syncthreads();

    // head: wave w computes output w of 4; lanes stride the 1400 features
    int sidb = sid[b];
    int wave = tid >> 6, lane = tid & 63;
    const float* wrow = hW + (sidb * 4 + wave) * 1400;
    float acc = 0.f;
    for (int f = lane; f < 1400; f += 64) acc += wrow[f] * p4s[f];
#pragma unroll
    for (int off = 32; off; off >>= 1) acc += __shfl_down(acc, off);
    if (lane == 0) out[b * 4 + wave] = acc + hB[sidb * 4 + wave];
}

extern "C" void kernel_launch(void* const* d_in, const int* in_sizes, int n_in,
                              void* d_out, int out_size, void* d_ws, size_t ws_size,
                              hipStream_t stream) {
    const float* x   = (const float*)d_in[0];
    const int*   sid = (const int*)d_in[1];
    const float* wt  = (const float*)d_in[2];
    const float* bt  = (const float*)d_in[3];
    const float* wsp = (const float*)d_in[4];
    const float* bsp = (const float*)d_in[5];
    const float* w2  = (const float*)d_in[6];
    const float* b2  = (const float*)d_in[7];
    const float* w3  = (const float*)d_in[8];
    const float* b3  = (const float*)d_in[9];
    const float* w4  = (const float*)d_in[10];
    const float* b4  = (const float*)d_in[11];
    const float* hW  = (const float*)d_in[12];
    const float* hB  = (const float*)d_in[13];
    float* out = (float*)d_out;
    float* ws  = (float*)d_ws;

    k_prep<<<22, 256, 0, stream>>>(wt, bt, wsp, bsp, ws);
    k_conv12<<<dim3(3, 256), 256, 0, stream>>>(x, ws, ws + WS_P1);
    k_rest<<<256, 256, 0, stream>>>(ws + WS_P1, w2, b2, w3, b3, w4, b4,
                                    hW, hB, sid, out);
}